// Round 1
// baseline (465.621 us; speedup 1.0000x reference)
//
#include <hip/hip_runtime.h>
#include <math.h>

#define BB   4096
#define KK   200
#define DD   128
#define FDIM 1024
#define MASK_FILL (-4294967295.0f)   // -(2^32)+1 in the reference; rounds to -2^32 in fp32

// ---------------- Kernel 1: target = target_feats @ W^T  ([B,FD] x [D,FD] -> [B,D])
__global__ __launch_bounds__(128) void target_gemm(const float* __restrict__ tf,
                                                   const float* __restrict__ W,
                                                   float* __restrict__ tgt) {
    __shared__ float s_tf[8 * FDIM];                   // 32 KiB: 8 batch rows
    const int tid = threadIdx.x;
    const size_t r0 = (size_t)blockIdx.x * 8;

    const float4* src = (const float4*)(tf + r0 * FDIM);
    for (int i = tid; i < 8 * FDIM / 4; i += 128)
        ((float4*)s_tf)[i] = src[i];
    __syncthreads();

    float acc[8] = {0, 0, 0, 0, 0, 0, 0, 0};
    const float4* wr = (const float4*)(W + (size_t)tid * FDIM);  // thread owns output col d=tid
    for (int f = 0; f < FDIM / 4; ++f) {
        float4 w = wr[f];
        #pragma unroll
        for (int r = 0; r < 8; ++r) {
            float4 t = ((const float4*)(s_tf + r * FDIM))[f];    // broadcast read
            acc[r] += w.x * t.x + w.y * t.y + w.z * t.z + w.w * t.w;
        }
    }
    #pragma unroll
    for (int r = 0; r < 8; ++r)
        tgt[(r0 + r) * DD + tid] = acc[r];
}

// ---------------- Kernel 2: fused masked-softmax attention over K neighbors, one block per b
__global__ __launch_bounds__(512) void attn(const float* __restrict__ nf,
                                            const float* __restrict__ nl,
                                            const int*   __restrict__ mask,
                                            const float* __restrict__ tgt,
                                            float* __restrict__ out) {
    __shared__ float  s_nf[KK * DD];      // 100 KiB: whole neighbor_feats row, read from HBM once
    __shared__ float  s_tgt[DD];
    __shared__ float  s_alpha[KK];
    __shared__ float  s_p[KK];
    __shared__ float4 s_rn[16][32];       // 8 KiB partial reductions (neighbor)
    __shared__ float4 s_rl[16][32];       // 8 KiB partial reductions (label)
    __shared__ float  s_stat[2];

    const int tid = threadIdx.x;
    const int b   = blockIdx.x;
    const float* nfb = nf + (size_t)b * KK * DD;
    const float* nlb = nl + (size_t)b * KK * DD;

    if (tid < DD / 4)
        ((float4*)s_tgt)[tid] = ((const float4*)(tgt + (size_t)b * DD))[tid];
    for (int i = tid; i < KK * DD / 4; i += 512)
        ((float4*)s_nf)[i] = ((const float4*)nfb)[i];
    __syncthreads();

    // ---- alpha[k] = <nf[b,k,:], target[b,:]>, masked
    const int wave = tid >> 6, lane = tid & 63;
    for (int k = wave; k < KK; k += 8) {
        float2 v = ((const float2*)(s_nf + k * DD))[lane];
        float2 t = ((const float2*)s_tgt)[lane];
        float d = v.x * t.x + v.y * t.y;
        #pragma unroll
        for (int off = 32; off > 0; off >>= 1)
            d += __shfl_xor(d, off);
        if (lane == 0)
            s_alpha[k] = (mask[(size_t)b * KK + k] > 0) ? d : MASK_FILL;
    }
    __syncthreads();

    // ---- softmax stats (wave 0)
    if (wave == 0) {
        float m = -INFINITY;
        for (int k = lane; k < KK; k += 64) m = fmaxf(m, s_alpha[k]);
        #pragma unroll
        for (int off = 32; off > 0; off >>= 1)
            m = fmaxf(m, __shfl_xor(m, off));
        float s = 0.0f;
        for (int k = lane; k < KK; k += 64) s += __expf(s_alpha[k] - m);
        #pragma unroll
        for (int off = 32; off > 0; off >>= 1)
            s += __shfl_xor(s, off);
        if (lane == 0) { s_stat[0] = m; s_stat[1] = s; }
    }
    __syncthreads();
    {
        const float m  = s_stat[0];
        const float iv = 1.0f / s_stat[1];
        if (tid < KK) s_p[tid] = __expf(s_alpha[tid] - m) * iv;
    }
    __syncthreads();

    // ---- weighted sums: nf from LDS, label streamed from HBM (float4 coalesced)
    const int c4  = tid & 31;    // float4 column (d = 4*c4)
    const int grp = tid >> 5;    // 0..15, strided over k
    float4 an = {0, 0, 0, 0}, al = {0, 0, 0, 0};
    const float4* nl4 = (const float4*)nlb;
    const float4* nf4 = (const float4*)s_nf;
    for (int k = grp; k < KK; k += 16) {
        float  p  = s_p[k];
        float4 vn = nf4[k * 32 + c4];
        float4 vl = nl4[k * 32 + c4];
        an.x += p * vn.x; an.y += p * vn.y; an.z += p * vn.z; an.w += p * vn.w;
        al.x += p * vl.x; al.y += p * vl.y; al.z += p * vl.z; al.w += p * vl.w;
    }
    s_rn[grp][c4] = an;
    s_rl[grp][c4] = al;
    __syncthreads();

    if (tid < 32) {
        float4 r = {0, 0, 0, 0};
        #pragma unroll
        for (int g = 0; g < 16; ++g) {
            float4 v = s_rn[g][tid];
            r.x += v.x; r.y += v.y; r.z += v.z; r.w += v.w;
        }
        ((float4*)(out + (size_t)b * DD))[tid] = r;
    } else if (tid < 64) {
        const int c = tid - 32;
        float4 r = {0, 0, 0, 0};
        #pragma unroll
        for (int g = 0; g < 16; ++g) {
            float4 v = s_rl[g][c];
            r.x += v.x; r.y += v.y; r.z += v.z; r.w += v.w;
        }
        ((float4*)(out + (size_t)BB * DD + (size_t)b * DD))[c] = r;
    }
}

extern "C" void kernel_launch(void* const* d_in, const int* in_sizes, int n_in,
                              void* d_out, int out_size, void* d_ws, size_t ws_size,
                              hipStream_t stream) {
    const float* tf   = (const float*)d_in[0];
    const float* nf   = (const float*)d_in[1];
    const float* nl   = (const float*)d_in[2];
    const int*   mask = (const int*)d_in[3];
    const float* W    = (const float*)d_in[4];
    float* out = (float*)d_out;
    float* tgt = (float*)d_ws;                 // needs B*D*4 = 2 MiB scratch

    target_gemm<<<BB / 8, 128, 0, stream>>>(tf, W, tgt);
    attn<<<BB, 512, 0, stream>>>(nf, nl, mask, tgt, out);
}

// Round 2
// 229.040 us; speedup vs baseline: 2.0329x; 2.0329x over previous
//
#include <hip/hip_runtime.h>
#include <math.h>

#define BB   4096
#define KK   200
#define DD   128
#define FDIM 1024
#define MASK_FILL (-4294967295.0f)   // -(2^32)+1, as fp32

// ---------------- Kernel 1: target = target_feats @ W^T  ([B,FD] x [D,FD] -> [B,D])
// 1024 blocks x 256 threads; 4 batch rows per block; FD split in half per thread.
__global__ __launch_bounds__(256) void target_gemm(const float* __restrict__ tf,
                                                   const float* __restrict__ W,
                                                   float* __restrict__ tgt) {
    __shared__ float s_tf[4 * FDIM];        // 16 KiB
    __shared__ float s_red[4][DD];          // 2 KiB (half h=1 partials)
    const int tid = threadIdx.x;
    const int d   = tid & 127;
    const int h   = tid >> 7;               // 0/1: which half of FD
    const size_t r0 = (size_t)blockIdx.x * 4;

    const float4* src = (const float4*)(tf + r0 * FDIM);
    for (int i = tid; i < 4 * FDIM / 4; i += 256)
        ((float4*)s_tf)[i] = src[i];
    __syncthreads();

    float acc[4] = {0, 0, 0, 0};
    const float4* wr = (const float4*)(W + (size_t)d * FDIM) + h * (FDIM / 8);
    #pragma unroll 4
    for (int i = 0; i < FDIM / 8; ++i) {
        float4 w = wr[i];
        #pragma unroll
        for (int r = 0; r < 4; ++r) {
            float4 t = ((const float4*)(s_tf + r * FDIM + h * (FDIM / 2)))[i];  // broadcast
            acc[r] += w.x * t.x + w.y * t.y + w.z * t.z + w.w * t.w;
        }
    }
    if (h == 1) {
        #pragma unroll
        for (int r = 0; r < 4; ++r) s_red[r][d] = acc[r];
    }
    __syncthreads();
    if (h == 0) {
        #pragma unroll
        for (int r = 0; r < 4; ++r)
            tgt[(r0 + r) * DD + d] = acc[r] + s_red[r][d];
    }
}

// ---------------- Kernel 2: fused masked-softmax attention, one block per b.
// neighbor_feats held in REGISTERS (13 float4/thread); nl streamed once.
__global__ __launch_bounds__(512, 4) void attn(const float* __restrict__ nf,
                                               const float* __restrict__ nl,
                                               const int*   __restrict__ mask,
                                               const float* __restrict__ tgt,
                                               float* __restrict__ out) {
    __shared__ float  s_alpha[KK];
    __shared__ float  s_p[KK];
    __shared__ float4 s_rn[16][32];
    __shared__ float4 s_rl[16][32];
    __shared__ float  s_stat[2];

    const int tid = threadIdx.x;
    const int b   = blockIdx.x;
    const int c4  = tid & 31;     // d-chunk: floats 4*c4 .. 4*c4+3
    const int grp = tid >> 5;     // k = grp + 16*i
    const float4* nf4 = (const float4*)(nf + (size_t)b * KK * DD);
    const float4* nl4 = (const float4*)(nl + (size_t)b * KK * DD);
    const int*    mb  = mask + (size_t)b * KK;

    const float4 tg = ((const float4*)(tgt + (size_t)b * DD))[c4];

    // ---- Phase 1: load nf into registers, alpha[k] = <nf[k,:], target>
    float4 vnf[13];
    #pragma unroll
    for (int i = 0; i < 13; ++i) {
        const int k = grp + 16 * i;
        if (k < KK) vnf[i] = nf4[k * 32 + c4];
    }
    #pragma unroll
    for (int i = 0; i < 13; ++i) {
        const int k = grp + 16 * i;
        if (k < KK) {
            float dsum = vnf[i].x * tg.x + vnf[i].y * tg.y + vnf[i].z * tg.z + vnf[i].w * tg.w;
            #pragma unroll
            for (int off = 16; off > 0; off >>= 1)
                dsum += __shfl_xor(dsum, off);
            if (c4 == 0)
                s_alpha[k] = (mb[k] > 0) ? dsum : MASK_FILL;
        }
    }
    __syncthreads();

    // ---- Phase 2: softmax over K (wave 0)
    if (tid < 64) {
        float m = -INFINITY;
        for (int k = tid; k < KK; k += 64) m = fmaxf(m, s_alpha[k]);
        #pragma unroll
        for (int off = 32; off > 0; off >>= 1)
            m = fmaxf(m, __shfl_xor(m, off));
        float s = 0.0f;
        for (int k = tid; k < KK; k += 64) s += __expf(s_alpha[k] - m);
        #pragma unroll
        for (int off = 32; off > 0; off >>= 1)
            s += __shfl_xor(s, off);
        if (tid == 0) { s_stat[0] = m; s_stat[1] = s; }
    }
    __syncthreads();
    {
        const float m  = s_stat[0];
        const float iv = 1.0f / s_stat[1];
        if (tid < KK) s_p[tid] = __expf(s_alpha[tid] - m) * iv;
    }
    __syncthreads();

    // ---- Phase 3: weighted sums; nf from registers, nl streamed from HBM
    float4 an = {0, 0, 0, 0}, al = {0, 0, 0, 0};
    #pragma unroll
    for (int i = 0; i < 13; ++i) {
        const int k = grp + 16 * i;
        if (k < KK) {
            const float  p  = s_p[k];
            const float4 vl = nl4[k * 32 + c4];
            an.x += p * vnf[i].x; an.y += p * vnf[i].y; an.z += p * vnf[i].z; an.w += p * vnf[i].w;
            al.x += p * vl.x;     al.y += p * vl.y;     al.z += p * vl.z;     al.w += p * vl.w;
        }
    }
    s_rn[grp][c4] = an;
    s_rl[grp][c4] = al;
    __syncthreads();

    if (tid < 32) {
        float4 r = {0, 0, 0, 0};
        #pragma unroll
        for (int g = 0; g < 16; ++g) {
            float4 v = s_rn[g][tid];
            r.x += v.x; r.y += v.y; r.z += v.z; r.w += v.w;
        }
        ((float4*)(out + (size_t)b * DD))[tid] = r;
    } else if (tid < 64) {
        const int c = tid - 32;
        float4 r = {0, 0, 0, 0};
        #pragma unroll
        for (int g = 0; g < 16; ++g) {
            float4 v = s_rl[g][c];
            r.x += v.x; r.y += v.y; r.z += v.z; r.w += v.w;
        }
        ((float4*)(out + (size_t)BB * DD + (size_t)b * DD))[c] = r;
    }
}

extern "C" void kernel_launch(void* const* d_in, const int* in_sizes, int n_in,
                              void* d_out, int out_size, void* d_ws, size_t ws_size,
                              hipStream_t stream) {
    const float* tf   = (const float*)d_in[0];
    const float* nf   = (const float*)d_in[1];
    const float* nl   = (const float*)d_in[2];
    const int*   mask = (const int*)d_in[3];
    const float* W    = (const float*)d_in[4];
    float* out = (float*)d_out;
    float* tgt = (float*)d_ws;                 // B*D*4 = 2 MiB scratch

    target_gemm<<<BB / 4, 256, 0, stream>>>(tf, W, tgt);
    attn<<<BB, 512, 0, stream>>>(nf, nl, mask, tgt, out);
}